// Round 2
// baseline (328.339 us; speedup 1.0000x reference)
//
#include <hip/hip_runtime.h>
#include <hip/hip_cooperative_groups.h>
#include <math.h>

namespace cg = cooperative_groups;

#define D 2048
#define EPS_COS 1e-8f
#define EPS_DEN 1e-6f
#define INV_TEMP 10.0f
#define TPB 256
#define WPB 4                   // waves per block, 1 row per wave per pass
#define FBLK 1024               // fused grid: 4 blocks/CU * 256 CU co-resident
#define NPASS 4                 // 1024 blocks * 4 waves * 4 passes = 16384 rows
#define NBLK 4096               // fallback two-kernel grid

// pos_pair: reference declares int64 but JAX x64-off makes it int32.
// Hedge: accept int32 reading iff plausible (in range, i != j), else int64.
__device__ __forceinline__ void get_ij(const int* __restrict__ p, int n,
                                       int& i, int& j) {
    int i32 = p[0], j32 = p[1];
    if (i32 >= 0 && i32 < n && j32 >= 0 && j32 < n && i32 != j32) {
        i = i32; j = j32; return;
    }
    const long long* p64 = (const long long*)p;
    i = (int)p64[0]; j = (int)p64[1];
}

// Fused single-launch kernel (cooperative): removes the loss_kernel dispatch
// and its launch/drain gap. 1024 blocks co-resident (launch_bounds(256,4)
// caps VGPR<=128 -> 4 blocks/CU guaranteed; LDS 8.2KB). Each wave streams 4
// rows (row0 + p*4096, contiguous 32MiB chunks per pass). Partials cross XCD
// boundaries -> agent-scope atomic store/load around grid.sync().
__global__ __launch_bounds__(TPB, 4)
void fused_kernel(const float* __restrict__ x, const int* __restrict__ pos,
                  float* __restrict__ part, float* __restrict__ nom,
                  float* __restrict__ out, int n) {
    int i, j;
    get_ij(pos, n, i, j);
    const int lane = threadIdx.x & 63;
    const int wave = threadIdx.x >> 6;
    const int t    = threadIdx.x;
    const int bid  = blockIdx.x;

    __shared__ float4 s_xi[D / 4];       // 8 KB anchor row
    __shared__ float  s_red[WPB];

    const float4* __restrict__ xi = (const float4*)(x + (size_t)i * D);
    float4 x0 = xi[t];
    float4 x1 = xi[t + 256];

    // pass-0 row loads issued while xi still in flight
    const int row0 = bid * WPB + wave;
    const float4* __restrict__ xr0 = (const float4*)(x + (size_t)row0 * D);
    float4 a[8];
#pragma unroll
    for (int w = 0; w < 8; ++w) a[w] = xr0[lane + w * 64];

    s_xi[t]       = x0;
    s_xi[t + 256] = x1;
    __syncthreads();

    float den_acc = 0.f;
    float ni_val  = 0.f;                 // valid on lane 0 after pass 0

#pragma unroll
    for (int p = 0; p < NPASS; ++p) {
        const int row = p * (FBLK * WPB) + row0;
        if (p > 0) {
            const float4* __restrict__ xr =
                (const float4*)(x + (size_t)row * D);
#pragma unroll
            for (int w = 0; w < 8; ++w) a[w] = xr[lane + w * 64];
        }
        float dot = 0.f, sq = 0.f, sqi = 0.f;
#pragma unroll
        for (int w = 0; w < 8; ++w) {
            const float4 b = s_xi[lane + w * 64];
            dot = fmaf(a[w].x, b.x, fmaf(a[w].y, b.y,
                  fmaf(a[w].z, b.z, fmaf(a[w].w, b.w, dot))));
            sq  = fmaf(a[w].x, a[w].x, fmaf(a[w].y, a[w].y,
                  fmaf(a[w].z, a[w].z, fmaf(a[w].w, a[w].w, sq))));
            if (p == 0)
                sqi = fmaf(b.x, b.x, fmaf(b.y, b.y,
                      fmaf(b.z, b.z, fmaf(b.w, b.w, sqi))));
        }
#pragma unroll
        for (int off = 32; off; off >>= 1) {
            dot += __shfl_down(dot, off);
            sq  += __shfl_down(sq,  off);
            if (p == 0) sqi += __shfl_down(sqi, off);
        }
        if (lane == 0) {
            if (p == 0) ni_val = fmaxf(sqrtf(sqi), EPS_COS);
            const float nk = fmaxf(sqrtf(sq), EPS_COS);
            const float e  = expf(INV_TEMP * dot / (nk * ni_val));
            if (row != i) den_acc += e;   // den includes k==j, excludes k==i
            if (row == j)
                __hip_atomic_store(nom, e, __ATOMIC_RELAXED,
                                   __HIP_MEMORY_SCOPE_AGENT);
        }
    }

    if (lane == 0) s_red[wave] = den_acc;
    __syncthreads();
    if (t == 0) {
        const float v = (s_red[0] + s_red[1]) + (s_red[2] + s_red[3]);
        __hip_atomic_store(&part[bid], v, __ATOMIC_RELAXED,
                           __HIP_MEMORY_SCOPE_AGENT);
    }

    cg::this_grid().sync();

    if (bid == 0) {
        float s = 0.f;
#pragma unroll
        for (int k = 0; k < FBLK / TPB; ++k)
            s += __hip_atomic_load(&part[t + k * TPB], __ATOMIC_RELAXED,
                                   __HIP_MEMORY_SCOPE_AGENT);
#pragma unroll
        for (int off = 32; off; off >>= 1) s += __shfl_down(s, off);
        if (lane == 0) s_red[wave] = s;
        __syncthreads();
        if (t == 0) {
            const float den = (s_red[0] + s_red[1]) + (s_red[2] + s_red[3]);
            const float nm  = __hip_atomic_load(nom, __ATOMIC_RELAXED,
                                                __HIP_MEMORY_SCOPE_AGENT);
            out[0] = -logf(nm / (den + EPS_DEN));
        }
    }
}

// ---------- fallback two-kernel path (unchanged from R1) ----------
__global__ __launch_bounds__(TPB)
void e_kernel(const float* __restrict__ x, const int* __restrict__ pos,
              float* __restrict__ part, float* __restrict__ nom, int n) {
    int i, j;
    get_ij(pos, n, i, j);
    const int lane = threadIdx.x & 63;
    const int wave = threadIdx.x >> 6;
    const int t    = threadIdx.x;
    const int row  = blockIdx.x * WPB + wave;

    const float4* __restrict__ xr = (const float4*)(x + (size_t)row * D);
    const float4* __restrict__ xi = (const float4*)(x + (size_t)i * D);

    __shared__ float4 s_xi[D / 4];
    __shared__ float  s_den[WPB];

    float4 x0 = xi[t];
    float4 x1 = xi[t + 256];

    float4 a[8];
#pragma unroll
    for (int w = 0; w < 8; ++w) a[w] = xr[lane + w * 64];

    s_xi[t]       = x0;
    s_xi[t + 256] = x1;
    __syncthreads();

    float dot = 0.f, sq = 0.f, sqi = 0.f;
#pragma unroll
    for (int w = 0; w < 8; ++w) {
        const float4 b = s_xi[lane + w * 64];
        dot = fmaf(a[w].x, b.x, fmaf(a[w].y, b.y,
              fmaf(a[w].z, b.z, fmaf(a[w].w, b.w, dot))));
        sq  = fmaf(a[w].x, a[w].x, fmaf(a[w].y, a[w].y,
              fmaf(a[w].z, a[w].z, fmaf(a[w].w, a[w].w, sq))));
        sqi = fmaf(b.x, b.x, fmaf(b.y, b.y,
              fmaf(b.z, b.z, fmaf(b.w, b.w, sqi))));
    }
#pragma unroll
    for (int off = 32; off; off >>= 1) {
        dot += __shfl_down(dot, off);
        sq  += __shfl_down(sq,  off);
        sqi += __shfl_down(sqi, off);
    }

    if (lane == 0) {
        float nk = fmaxf(sqrtf(sq),  EPS_COS);
        float ni = fmaxf(sqrtf(sqi), EPS_COS);
        float e  = expf(INV_TEMP * dot / (nk * ni));
        s_den[wave] = (row != i) ? e : 0.f;
        if (row == j) *nom = e;
    }
    __syncthreads();
    if (t == 0)
        part[blockIdx.x] = (s_den[0] + s_den[1]) + (s_den[2] + s_den[3]);
}

__global__ __launch_bounds__(1024)
void loss_kernel(const float* __restrict__ part, const float* __restrict__ nom,
                 float* __restrict__ out) {
    const int t = threadIdx.x;
    const float4 v = ((const float4*)part)[t];
    float s = (v.x + v.y) + (v.z + v.w);
#pragma unroll
    for (int off = 32; off; off >>= 1) s += __shfl_down(s, off);

    __shared__ float ls[16];
    if ((t & 63) == 0) ls[t >> 6] = s;
    __syncthreads();

    if (t == 0) {
        float den = 0.f;
#pragma unroll
        for (int w = 0; w < 16; ++w) den += ls[w];
        out[0] = -logf(nom[0] / (den + EPS_DEN));
    }
}

extern "C" void kernel_launch(void* const* d_in, const int* in_sizes, int n_in,
                              void* d_out, int out_size, void* d_ws, size_t ws_size,
                              hipStream_t stream) {
    const float* x    = (const float*)d_in[0];
    const int*   pos  = (const int*)d_in[1];
    float*       out  = (float*)d_out;
    float*       part = (float*)d_ws;              // partials (<=4096 slots)
    float*       nom  = (float*)d_ws + NBLK;       // e_j slot
    int          n    = in_sizes[0] / D;           // 16384

    void* args[6] = {(void*)&x, (void*)&pos, (void*)&part,
                     (void*)&nom, (void*)&out, (void*)&n};
    hipError_t err = hipLaunchCooperativeKernel(
        reinterpret_cast<const void*>(&fused_kernel),
        dim3(FBLK), dim3(TPB), args, 0, stream);

    if (err != hipSuccess) {
        // fallback: classic two-dispatch path
        e_kernel<<<NBLK, TPB, 0, stream>>>(x, pos, part, nom, n);
        loss_kernel<<<1, 1024, 0, stream>>>(part, nom, out);
    }
}

// Round 3
// 177.710 us; speedup vs baseline: 1.8476x; 1.8476x over previous
//
#include <hip/hip_runtime.h>
#include <math.h>

#define D 2048
#define EPS_COS 1e-8f
#define EPS_DEN 1e-6f
#define INV_TEMP 10.0f
#define TPB 256
#define WPB 4                   // waves per block, 1 row per wave
#define NBLK 4096               // 4096 blocks * 4 rows = 16384 rows

typedef float f4 __attribute__((ext_vector_type(4)));

// pos_pair: reference declares int64 but JAX x64-off makes it int32.
// Hedge: accept int32 reading iff plausible (in range, i != j), else int64.
__device__ __forceinline__ void get_ij(const int* __restrict__ p, int n,
                                       int& i, int& j) {
    int i32 = p[0], j32 = p[1];
    if (i32 >= 0 && i32 < n && j32 >= 0 && j32 < n && i32 != j32) {
        i = i32; j = j32; return;
    }
    const long long* p64 = (const long long*)p;
    i = (int)p64[0]; j = (int)p64[1];
}

// Kernel 1 (R1 structure, proven 187.2us): one row per wave, xi staged in
// LDS once per block. Row loads are NON-TEMPORAL: each x row is read exactly
// once and the harness's 512MiB poison fills recycle L2/L3 every iteration,
// so caching the stream is pure overhead. xi loads stay cached.
// R2 lesson (VGPR=36, 383 GB/s): do NOT wrap this in a multi-pass loop or
// grid-sync — the batched a[8] in-flight loads are what make it fast.
__global__ __launch_bounds__(TPB)
void e_kernel(const float* __restrict__ x, const int* __restrict__ pos,
              float* __restrict__ part, float* __restrict__ nom, int n) {
    int i, j;
    get_ij(pos, n, i, j);
    const int lane = threadIdx.x & 63;
    const int wave = threadIdx.x >> 6;
    const int t    = threadIdx.x;
    const int row  = blockIdx.x * WPB + wave;

    const f4* __restrict__ xr = (const f4*)(x + (size_t)row * D);
    const f4* __restrict__ xi = (const f4*)(x + (size_t)i * D);

    __shared__ f4    s_xi[D / 4];        // 8 KB anchor row
    __shared__ float s_den[WPB];

    // xi loads first (2 per thread covers 512 f4), normal/cached
    f4 x0 = xi[t];
    f4 x1 = xi[t + 256];

    // row loads: 8 f4 per lane, non-temporal, issued while xi in flight
    f4 a[8];
#pragma unroll
    for (int w = 0; w < 8; ++w)
        a[w] = __builtin_nontemporal_load(&xr[lane + w * 64]);

    s_xi[t]       = x0;
    s_xi[t + 256] = x1;
    __syncthreads();

    float dot = 0.f, sq = 0.f, sqi = 0.f;
#pragma unroll
    for (int w = 0; w < 8; ++w) {
        const f4 b = s_xi[lane + w * 64];
        dot = fmaf(a[w].x, b.x, fmaf(a[w].y, b.y,
              fmaf(a[w].z, b.z, fmaf(a[w].w, b.w, dot))));
        sq  = fmaf(a[w].x, a[w].x, fmaf(a[w].y, a[w].y,
              fmaf(a[w].z, a[w].z, fmaf(a[w].w, a[w].w, sq))));
        sqi = fmaf(b.x, b.x, fmaf(b.y, b.y,
              fmaf(b.z, b.z, fmaf(b.w, b.w, sqi))));
    }
#pragma unroll
    for (int off = 32; off; off >>= 1) {
        dot += __shfl_down(dot, off);
        sq  += __shfl_down(sq,  off);
        sqi += __shfl_down(sqi, off);
    }

    if (lane == 0) {
        float nk = fmaxf(sqrtf(sq),  EPS_COS);
        float ni = fmaxf(sqrtf(sqi), EPS_COS);
        float e  = expf(INV_TEMP * dot / (nk * ni));
        s_den[wave] = (row != i) ? e : 0.f;   // den includes k==j, excludes k==i
        if (row == j) *nom = e;
    }
    __syncthreads();
    if (t == 0)
        part[blockIdx.x] = (s_den[0] + s_den[1]) + (s_den[2] + s_den[3]);
}

// Kernel 2: one block sums 4096 partials (16 KB, L2-hot) + finishes loss.
__global__ __launch_bounds__(1024)
void loss_kernel(const float* __restrict__ part, const float* __restrict__ nom,
                 float* __restrict__ out) {
    const int t = threadIdx.x;
    const f4 v = ((const f4*)part)[t];     // 1024 f4 = 4096 floats
    float s = (v.x + v.y) + (v.z + v.w);
#pragma unroll
    for (int off = 32; off; off >>= 1) s += __shfl_down(s, off);

    __shared__ float ls[16];
    if ((t & 63) == 0) ls[t >> 6] = s;
    __syncthreads();

    if (t == 0) {
        float den = 0.f;
#pragma unroll
        for (int w = 0; w < 16; ++w) den += ls[w];
        out[0] = -logf(nom[0] / (den + EPS_DEN));
    }
}

extern "C" void kernel_launch(void* const* d_in, const int* in_sizes, int n_in,
                              void* d_out, int out_size, void* d_ws, size_t ws_size,
                              hipStream_t stream) {
    const float* x    = (const float*)d_in[0];
    const int*   pos  = (const int*)d_in[1];
    float*       out  = (float*)d_out;
    float*       part = (float*)d_ws;              // [0..4095] block partials
    float*       nom  = (float*)d_ws + NBLK;       // e_j slot

    const int n = in_sizes[0] / D;                 // 16384

    e_kernel<<<NBLK, TPB, 0, stream>>>(x, pos, part, nom, n);
    loss_kernel<<<1, 1024, 0, stream>>>(part, nom, out);
}